// Round 1
// baseline (634.162 us; speedup 1.0000x reference)
//
#include <hip/hip_runtime.h>

// NeighborSample: x[8,64,64,192] f32 -> out[8*64*64, 5, 5, 192] f32
//
// R5: LDS-staged GATHER with a perfectly LINEAR output sweep.
//
// R4 (scatter) read the input once but emitted 25 interleaved write streams
// per wave (taps spread over a +/-1.2 MB window); measured kernel time
// ~226 us for 654 MB of ideal traffic => ~2.9 TB/s, while the harness's own
// fillBuffer sustains 6.2 TB/s on the same output buffer with a linear
// sweep. Theory: scattered-order 64B-granule write traffic halves DRAM/L2
// write-back efficiency; the fix is to make the write stream linear.
//
// Structure: out[p][oi][oj][c] == in[y+oi-2][x+oj-2][c] (zero-padded), so an
// output pixel row (19,200 B) is the concatenation of the 25 neighbor
// channel-rows (768 B each). Each block stages the [5 rows][20 cols][48 f4]
// halo window of 16 x-consecutive pixels into LDS (76.8 KB, fine on gfx950:
// 160 KB/CU, 2 blocks/CU), then writes its 16*19,200 B = 307 KB output
// chunk as one contiguous stream, sourcing from LDS. LDS read addresses are
// consecutive across oj/k4 (col stride == C4), jumping only at oi/pixel
// boundaries -> standard conflict-light ds_read_b128 pattern.
//
// Traffic: write 629 MB linear (exactly the fill's pattern) + stage reads
// 2048 * 76.8 KB = 157 MB, mostly L3 hits (input is 24 MB < 256 MB L3).

typedef float f32x4 __attribute__((ext_vector_type(4)));

constexpr int B = 8;
constexpr int H = 64;
constexpr int W = 64;
constexpr int C4 = 48;               // 192 ch / 4 = float4 per pixel-channel row
constexpr int K = 5;
constexpr int PAD = K / 2;
constexpr int ROW = K * K * C4;      // 1200 float4 per output pixel

constexpr int TP   = 16;             // x-consecutive pixels per block
constexpr int WIN  = TP + 2 * PAD;   // 20 staged input cols
constexpr int WROW = WIN * C4;       // 960 float4 per staged row (= 15 waves)
constexpr int LDSF4 = K * WROW;      // 4800 float4 = 76,800 B LDS
constexpr int OUTF4 = TP * ROW;      // 19200 float4 output per block (75 iters)

constexpr int BLOCK = 256;
constexpr unsigned NBLK = (unsigned)B * H * (W / TP);   // 2048 blocks

__global__ __launch_bounds__(BLOCK) void neighbor_lds_kernel(
    const f32x4* __restrict__ in, f32x4* __restrict__ out) {
  __shared__ f32x4 lds[LDSF4];

  const int tid = (int)threadIdx.x;
  const unsigned blk = blockIdx.x;
  const int xblk = (int)(blk & (W / TP - 1));   // 4 x-blocks per row
  const int y    = (int)((blk >> 2) & (H - 1));
  const int b    = (int)(blk >> 8);
  const int x0   = xblk * TP;

  // ---- stage [5][WIN][C4] halo window into LDS (zero-padded) ----
  const bool interior =
      (y >= PAD) & (y < H - PAD) & (x0 >= PAD) & (x0 + TP + PAD <= W);

  if (interior) {
    // Window rows are contiguous 960-f4 runs in global memory; 960 = 15*64
    // so every wave's 64 lanes read one contiguous, row-aligned 1 KB chunk.
    const f32x4* src = in + ((b * H + (y - PAD)) * W + (x0 - PAD)) * C4;
    for (int i = tid; i < LDSF4; i += BLOCK) {
      int r   = i / WROW;
      int rem = i - r * WROW;
      lds[i] = src[r * (W * C4) + rem];
    }
  } else {
    for (int i = tid; i < LDSF4; i += BLOCK) {
      int r   = i / WROW;
      int rem = i - r * WROW;
      int col = rem / C4;
      int k4  = rem - col * C4;
      int ys = y + r - PAD;
      int xs = x0 + col - PAD;
      f32x4 v = {0.f, 0.f, 0.f, 0.f};
      if ((unsigned)ys < (unsigned)H && (unsigned)xs < (unsigned)W)
        v = in[((b * H + ys) * W + xs) * C4 + k4];
      lds[i] = v;
    }
  }
  __syncthreads();

  // ---- linear write sweep: one contiguous 307 KB stream per block ----
  f32x4* dst = out + (size_t)((b * H + y) * W + x0) * ROW;

  // Decompose j = pl*1200 + tap*48 + k4; maintained incrementally
  // (j += 256  <=>  k4 += 16, tap += 5, with carries).  tid < 256 => pl0 = 0.
  int tap = tid / C4;
  int k4  = tid - tap * C4;
  int pl  = 0;

#pragma unroll 5
  for (int j = tid; j < OUTF4; j += BLOCK) {
    int oi = (tap * 205) >> 10;        // tap / 5  (exact for tap in [0,25))
    int oj = tap - oi * 5;
    dst[j] = lds[(oi * WIN + pl + oj) * C4 + k4];
    k4  += BLOCK % C4;                 // +16
    tap += BLOCK / C4;                 // +5
    if (k4 >= C4)   { k4 -= C4; ++tap; }
    if (tap >= K*K) { tap -= K*K; ++pl; }
  }
}

extern "C" void kernel_launch(void* const* d_in, const int* in_sizes, int n_in,
                              void* d_out, int out_size, void* d_ws, size_t ws_size,
                              hipStream_t stream) {
  const f32x4* in = (const f32x4*)d_in[0];
  f32x4* out = (f32x4*)d_out;
  neighbor_lds_kernel<<<NBLK, BLOCK, 0, stream>>>(in, out);
}